// Round 5
// baseline (152.405 us; speedup 1.0000x reference)
//
#include <hip/hip_runtime.h>

// Problem constants
#define T_STEPS 128
#define BATCH   64
#define DIMX    32
#define S_SUP   1024
#define NROW    8192          // T*B
#define OUT_H_SZ   (T_STEPS*BATCH*4)      // 32768
#define OUT_RBF_SZ (NROW*S_SUP)           // 8388608
#define N_LSTM_BLK 16                     // 4 batch chains per block

__device__ __forceinline__ float rcp_fast(float x) { return __builtin_amdgcn_rcpf(x); }

// Intra-quad broadcast via DPP quad_perm (VALU latency, vs ~120 cy ds_bpermute)
template<int K>
__device__ __forceinline__ float quad_bcast(float v) {
    constexpr int ctrl = K * 0x55;   // K | K<<2 | K<<4 | K<<6
    return __builtin_bit_cast(float,
        __builtin_amdgcn_mov_dpp(__builtin_bit_cast(int, v), ctrl, 0xF, 0xF, true));
}

// ---------------------------------------------------------------------------
// Kernel 1: pre-activations, written in LSTM-block-contiguous layout:
//   float4 index = (k*128 + t)*16 + b_local*4 + g,  k = b>>2, b_local = b&3
// so block k's slice (4 batches, all 128 steps) is one contiguous 32 KB run.
// ---------------------------------------------------------------------------
__global__ __launch_bounds__(256) void pre_kernel(
    const float* __restrict__ x,
    const float* __restrict__ Wf, const float* __restrict__ bf,
    const float* __restrict__ Wi, const float* __restrict__ bi,
    const float* __restrict__ Wu, const float* __restrict__ bu,
    const float* __restrict__ Wo, const float* __restrict__ bo,
    const float* __restrict__ pf, const float* __restrict__ pi,
    const float* __restrict__ pu, const float* __restrict__ po,
    float* __restrict__ pre)
{
    const int tid = threadIdx.x;
    const int rl  = tid >> 4;          // 16 rows per block
    const int gw  = tid & 15;
    const int g   = gw >> 2, w = gw & 3;
    const int row = blockIdx.x * 16 + rl;     // row = t*64 + b
    const int t   = row >> 6;
    const int b   = row & 63;

    __shared__ float xs[16 * DIMX];
    if (tid < 128) {
        ((float4*)xs)[tid] = ((const float4*)(x + (size_t)blockIdx.x * 16 * DIMX))[tid];
    }
    __syncthreads();

    const float* W  = (g == 0) ? Wf : (g == 1) ? Wi : (g == 2) ? Wu : Wo;
    const float* bb = (g == 0) ? bf : (g == 1) ? bi : (g == 2) ? bu : bo;
    const float* pp = (g == 0) ? pf : (g == 1) ? pi : (g == 2) ? pu : po;

    float acc = bb[w] + pp[w];
    const float* Wr = W + w * 36;      // row stride D+H = 36
    const float* xr = xs + rl * DIMX;
#pragma unroll
    for (int d = 0; d < DIMX; d++) acc += xr[d] * Wr[d];

    // block-contiguous layout
    const size_t fidx = ((size_t)((b >> 2) * 128 + t) * 16 + (b & 3) * 4 + g) * 4 + w;
    pre[fidx] = acc;
}

// ---------------------------------------------------------------------------
// Kernel 2 (fused): blocks 0..15 = LSTM (4 batch chains each, pre slice in
// LDS), blocks 16..527 = rbf+qk tiles
// ---------------------------------------------------------------------------
__global__ __launch_bounds__(256) void fused_kernel(
    const float* __restrict__ x,  const float* __restrict__ sv,
    const float* __restrict__ Wf, const float* __restrict__ Wi,
    const float* __restrict__ Wu, const float* __restrict__ Wo,
    const float* __restrict__ qkp, const float* __restrict__ pre,
    float* __restrict__ out_h, float* __restrict__ out_rbf, float* __restrict__ out_qk)
{
    // 33 KB shared: LSTM uses smem4[0..2047] (32 KB pre slice);
    // rbf uses first 8 KB as x tile + smem4[2048..2063] as xn2
    __shared__ float4 smem4[2064];
    const int tid = threadIdx.x;

    if (blockIdx.x < N_LSTM_BLK) {
        // ======== LSTM: stage 32 KB pre slice -> LDS, then 128 steps =======
        const int k = blockIdx.x;
        const float4* src = (const float4*)pre + (size_t)k * 2048;
#pragma unroll
        for (int i = 0; i < 8; i++)
            smem4[i * 256 + tid] = src[i * 256 + tid];
        __syncthreads();
        if (tid >= 16) return;               // 16 lanes = 4 batches x 4 gates

        __builtin_amdgcn_s_setprio(3);       // latency-critical wave
        const int lane = tid, g = lane & 3;
        const float* W = (g == 0) ? Wf : (g == 1) ? Wi : (g == 2) ? Wu : Wo;

        float Wh[4][4];                      // hidden part W[w][32+j]
#pragma unroll
        for (int w = 0; w < 4; w++)
#pragma unroll
            for (int j = 0; j < 4; j++) Wh[w][j] = W[w * 36 + 32 + j];

        // per-lane activation constants: g==2 -> tanh = 2*sigmoid(2x)-1
        const float kexp = (g == 2) ? -2.f : -1.f;
        const float Aa   = (g == 2) ?  2.f :  1.f;
        const float Bb   = (g == 2) ? -1.f :  0.f;
        const bool  isg1 = (g == 1), isg2 = (g == 2), isg3 = (g == 3);

        float h0 = 0.f, h1 = 0.f, h2 = 0.f, h3 = 0.f;
        float c0 = 0.f, c1 = 0.f, c2 = 0.f, c3 = 0.f;

        // 2-deep LDS prefetch (ds_read ~120 cy << old ~900 cy L3 latency)
        float4 cur = smem4[lane];            // t = 0
        float4 nxt = smem4[16 + lane];       // t = 1

#pragma unroll 2
        for (int t = 0; t < T_STEPS; t++) {
            const int ta = (t + 2 > T_STEPS - 1) ? (T_STEPS - 1) : (t + 2);
            float4 after = smem4[ta * 16 + lane];

            float a0 = cur.x, a1 = cur.y, a2 = cur.z, a3 = cur.w;
            // hidden contribution
            a0 += h0 * Wh[0][0] + h1 * Wh[0][1] + h2 * Wh[0][2] + h3 * Wh[0][3];
            a1 += h0 * Wh[1][0] + h1 * Wh[1][1] + h2 * Wh[1][2] + h3 * Wh[1][3];
            a2 += h0 * Wh[2][0] + h1 * Wh[2][1] + h2 * Wh[2][2] + h3 * Wh[2][3];
            a3 += h0 * Wh[3][0] + h1 * Wh[3][1] + h2 * Wh[3][2] + h3 * Wh[3][3];

            // closed-form circuit: C_w = cos(angle_w); PERM_WRAP-conjugated Z
            float C0 = __cosf(a0), C1 = __cosf(a1), C2 = __cosf(a2), C3 = __cosf(a3);
            float t23 = C2 * C3;
            float m01 = C0 * C1;
            float r0 = C1 * t23;     // <Z0> = C1 C2 C3
            float r1 = m01;          // <Z1> = C0 C1
            float r2 = m01 * C2;     // <Z2> = C0 C1 C2
            float r3 = m01 * t23;    // <Z3> = C0 C1 C2 C3

            // activation (sigmoid, or tanh for g==2), branch-free per-lane consts
            float o0 = Aa * rcp_fast(1.f + __expf(r0 * kexp)) + Bb;
            float o1 = Aa * rcp_fast(1.f + __expf(r1 * kexp)) + Bb;
            float o2 = Aa * rcp_fast(1.f + __expf(r2 * kexp)) + Bb;
            float o3 = Aa * rcp_fast(1.f + __expf(r3 * kexp)) + Bb;

            // gather f/i/u/o vectors from quad lanes (g = 0,1,2,3) via DPP
            float f0 = quad_bcast<0>(o0), f1 = quad_bcast<0>(o1), f2 = quad_bcast<0>(o2), f3 = quad_bcast<0>(o3);
            float i0 = quad_bcast<1>(o0), i1 = quad_bcast<1>(o1), i2 = quad_bcast<1>(o2), i3 = quad_bcast<1>(o3);
            float u0 = quad_bcast<2>(o0), u1 = quad_bcast<2>(o1), u2 = quad_bcast<2>(o2), u3 = quad_bcast<2>(o3);
            float z0 = quad_bcast<3>(o0), z1 = quad_bcast<3>(o1), z2 = quad_bcast<3>(o2), z3 = quad_bcast<3>(o3);

            c0 = f0 * c0 + i0 * u0;
            c1 = f1 * c1 + i1 * u1;
            c2 = f2 * c2 + i2 * u2;
            c3 = f3 * c3 + i3 * u3;

            float t0 = 2.f * rcp_fast(1.f + __expf(-2.f * c0)) - 1.f;
            float t1 = 2.f * rcp_fast(1.f + __expf(-2.f * c1)) - 1.f;
            float t2 = 2.f * rcp_fast(1.f + __expf(-2.f * c2)) - 1.f;
            float t3 = 2.f * rcp_fast(1.f + __expf(-2.f * c3)) - 1.f;
            h0 = z0 * t0; h1 = z1 * t1; h2 = z2 * t2; h3 = z3 * t3;

            // h is quad-uniform: lane (b_local,g) stores component g
            float hsel = isg1 ? h1 : h0;
            hsel = isg2 ? h2 : hsel;
            hsel = isg3 ? h3 : hsel;
            out_h[t * 256 + k * 16 + lane] = hsel;   // [t][b][g], 64 B run

            cur = nxt; nxt = after;
        }
    } else {
        // ================= rbf + qk tile: 64 n x 256 s =====================
        float* xs  = (float*)smem4;          // 8 KB x tile
        float* xn2 = (float*)(smem4 + 2048); // 64 floats
        const int bid = blockIdx.x - N_LSTM_BLK;
        const int n0  = (bid >> 2) * BATCH;
        const int s0  = (bid & 3) * 256;

        float4* xs4 = (float4*)xs;
        const float4* xg = (const float4*)(x + (size_t)n0 * DIMX);
        float4 t0v = xg[tid];
        float4 t1v = xg[tid + 256];
        xs4[tid]       = t0v;
        xs4[tid + 256] = t1v;

        // per-row |x|^2 from staging registers: 8 lanes per row, xor-reduce
        float p0 = t0v.x * t0v.x + t0v.y * t0v.y + t0v.z * t0v.z + t0v.w * t0v.w;
        float p1 = t1v.x * t1v.x + t1v.y * t1v.y + t1v.z * t1v.z + t1v.w * t1v.w;
        p0 += __shfl_xor(p0, 1); p1 += __shfl_xor(p1, 1);
        p0 += __shfl_xor(p0, 2); p1 += __shfl_xor(p1, 2);
        p0 += __shfl_xor(p0, 4); p1 += __shfl_xor(p1, 4);
        if ((tid & 7) == 0) {
            xn2[tid >> 3]        = p0;   // rows 0..31
            xn2[(tid >> 3) + 32] = p1;   // rows 32..63
        }

        const int s = s0 + tid;              // this thread's support vector
        float4 svv[8];
        const float4* svg = (const float4*)(sv + (size_t)s * DIMX);
#pragma unroll
        for (int k = 0; k < 8; k++) svv[k] = svg[k];
        float sn2 = 0.f;
#pragma unroll
        for (int k = 0; k < 8; k++)
            sn2 += svv[k].x * svv[k].x + svv[k].y * svv[k].y + svv[k].z * svv[k].z + svv[k].w * svv[k].w;

        // qk s-side: B_w = sv_w/2 + qk_w   (PERM_LINE drops out of sx@sy.T)
        const float B0 = 0.5f * svv[0].x + qkp[0];
        const float B1 = 0.5f * svv[0].y + qkp[1];
        const float B2 = 0.5f * svv[0].z + qkp[2];
        const float B3 = 0.5f * svv[0].w + qkp[3];
        __syncthreads();

#pragma unroll 4
        for (int n = 0; n < BATCH; n++) {
            const float4* xr4 = (const float4*)(xs + n * DIMX);   // broadcast reads
            float4 xv0 = xr4[0];
            float dot = xv0.x * svv[0].x + xv0.y * svv[0].y + xv0.z * svv[0].z + xv0.w * svv[0].w;
#pragma unroll
            for (int k = 1; k < 8; k++) {
                float4 xv = xr4[k];
                dot += xv.x * svv[k].x + xv.y * svv[k].y + xv.z * svv[k].z + xv.w * svv[k].w;
            }
            float dist = xn2[n] + sn2 - 2.f * dot;
            float rb   = __expf(-dist);

            float qv = __cosf(0.5f * xv0.x + B0) * __cosf(0.5f * xv0.y + B1)
                     * __cosf(0.5f * xv0.z + B2) * __cosf(0.5f * xv0.w + B3);
            qv = fabsf(qv);

            const int row = n0 + n;
            out_rbf[(size_t)row * S_SUP + s] = rb;
            out_qk [(size_t)row * S_SUP + s] = qv;
        }
    }
}

// ---------------------------------------------------------------------------
extern "C" void kernel_launch(void* const* d_in, const int* in_sizes, int n_in,
                              void* d_out, int out_size, void* d_ws, size_t ws_size,
                              hipStream_t stream)
{
    const float* x   = (const float*)d_in[0];
    const float* sv  = (const float*)d_in[1];
    const float* Wf  = (const float*)d_in[2];
    const float* bf  = (const float*)d_in[3];
    const float* Wi  = (const float*)d_in[4];
    const float* bi  = (const float*)d_in[5];
    const float* Wu  = (const float*)d_in[6];
    const float* bu  = (const float*)d_in[7];
    const float* Wo  = (const float*)d_in[8];
    const float* bo  = (const float*)d_in[9];
    const float* pf  = (const float*)d_in[10];
    const float* pi  = (const float*)d_in[11];
    const float* pu  = (const float*)d_in[12];
    const float* po  = (const float*)d_in[13];
    const float* qkp = (const float*)d_in[14];

    float* out     = (float*)d_out;
    float* out_h   = out;
    float* out_rbf = out + OUT_H_SZ;
    float* out_qk  = out + OUT_H_SZ + OUT_RBF_SZ;

    float* pre = (float*)d_ws;   // 512 KB scratch (NROW*16 floats)

    pre_kernel<<<NROW / 16, 256, 0, stream>>>(x, Wf, bf, Wi, bi, Wu, bu, Wo, bo,
                                              pf, pi, pu, po, pre);
    fused_kernel<<<N_LSTM_BLK + 512, 256, 0, stream>>>(
        x, sv, Wf, Wi, Wu, Wo, qkp, pre,
        out_h, out_rbf, out_qk);
}